// Round 11
// baseline (229.286 us; speedup 1.0000x reference)
//
#include <hip/hip_runtime.h>
#include <math.h>

#define SS 2048
#define DD 1280
#define HH 16
#define HDD 80
#define ND3 3840

typedef __attribute__((ext_vector_type(8))) short short8;
typedef __attribute__((ext_vector_type(4))) short s16x4;
typedef __attribute__((ext_vector_type(4))) float f32x4;
typedef __attribute__((ext_vector_type(8))) _Float16 h16x8;
typedef __attribute__((ext_vector_type(4))) _Float16 h16x4;

__device__ inline short f2bf(float f) {
    union { float f; unsigned u; } x; x.f = f;
    unsigned r = x.u + 0x7FFF + ((x.u >> 16) & 1);
    return (short)(r >> 16);
}

__device__ inline h16x8 cvt8(float4 a, float4 b) {
    h16x8 f;
    f[0] = (_Float16)a.x; f[1] = (_Float16)a.y;
    f[2] = (_Float16)a.z; f[3] = (_Float16)a.w;
    f[4] = (_Float16)b.x; f[5] = (_Float16)b.y;
    f[6] = (_Float16)b.z; f[7] = (_Float16)b.w;
    return f;
}

#define LDSA(m, kg) ((m) * 32 + (((kg) ^ (((m) >> 1) & 3)) << 3))

// ---- fp16 MFMA GEMM, fp32 inputs converted inline at LDS staging ----
// C = A @ B^T + bias (fp32 out). R4/R8-proven structure: 4 waves 2x2, BK=32,
// swizzled LDS, register prefetch, plain stores.
template <int BMT, int BNT>
__global__ __launch_bounds__(256) void gemm_f32ab(
    const float* __restrict__ A, const float* __restrict__ B,
    const float* __restrict__ bias, float* __restrict__ C,
    int M, int N, int K)
{
    constexpr int IT = BMT / 32;
    constexpr int JT = BNT / 32;
    constexpr int AU = BMT / 64;
    constexpr int BU = BNT / 64;
    __shared__ _Float16 AhS[BMT * 32];
    __shared__ _Float16 BhS[BNT * 32];

    const int tid = threadIdx.x;
    const int w = tid >> 6;
    const int lane = tid & 63;
    const int l15 = lane & 15;
    const int quad = lane >> 4;
    const int wm = w >> 1, wn = w & 1;
    const int bm = blockIdx.y * BMT;
    const int bn = blockIdx.x * BNT;

    f32x4 acc[IT][JT];
    #pragma unroll
    for (int i = 0; i < IT; ++i)
        #pragma unroll
        for (int j = 0; j < JT; ++j)
            acc[i][j] = (f32x4){0.f, 0.f, 0.f, 0.f};

    float4 rah[AU][2], rbh[BU][2];
    auto loadg = [&](int k0) {
        #pragma unroll
        for (int u = 0; u < AU; ++u) {
            int c = tid + u * 256, m = c >> 2, kg = c & 3;
            size_t off = (size_t)(bm + m) * K + k0 + kg * 8;
            rah[u][0] = *(const float4*)(A + off);
            rah[u][1] = *(const float4*)(A + off + 4);
        }
        #pragma unroll
        for (int u = 0; u < BU; ++u) {
            int c = tid + u * 256, m = c >> 2, kg = c & 3;
            size_t off = (size_t)(bn + m) * K + k0 + kg * 8;
            rbh[u][0] = *(const float4*)(B + off);
            rbh[u][1] = *(const float4*)(B + off + 4);
        }
    };

    loadg(0);
    for (int k0 = 0; k0 < K; k0 += 32) {
        __syncthreads();
        #pragma unroll
        for (int u = 0; u < AU; ++u) {
            int c = tid + u * 256, m = c >> 2, kg = c & 3;
            *(h16x8*)&AhS[LDSA(m, kg)] = cvt8(rah[u][0], rah[u][1]);
        }
        #pragma unroll
        for (int u = 0; u < BU; ++u) {
            int c = tid + u * 256, m = c >> 2, kg = c & 3;
            *(h16x8*)&BhS[LDSA(m, kg)] = cvt8(rbh[u][0], rbh[u][1]);
        }
        __syncthreads();
        if (k0 + 32 < K) loadg(k0 + 32);

        h16x8 af[IT], bf[JT];
        #pragma unroll
        for (int i = 0; i < IT; ++i) {
            int m = wm * (BMT / 2) + i * 16 + l15;
            af[i] = *(h16x8*)&AhS[LDSA(m, quad)];
        }
        #pragma unroll
        for (int j = 0; j < JT; ++j) {
            int n = wn * (BNT / 2) + j * 16 + l15;
            bf[j] = *(h16x8*)&BhS[LDSA(n, quad)];
        }
        #pragma unroll
        for (int i = 0; i < IT; ++i)
            #pragma unroll
            for (int j = 0; j < JT; ++j)
                acc[i][j] = __builtin_amdgcn_mfma_f32_16x16x32_f16(af[i], bf[j], acc[i][j], 0, 0, 0);
    }

    #pragma unroll
    for (int j = 0; j < JT; ++j) {
        int col = bn + wn * (BNT / 2) + j * 16 + l15;
        float bb = bias[col];
        #pragma unroll
        for (int i = 0; i < IT; ++i)
            #pragma unroll
            for (int r = 0; r < 4; ++r) {
                int row = bm + wm * (BMT / 2) + i * 16 + quad * 4 + r;
                C[(size_t)row * N + col] = acc[i][j][r] + bb;
            }
    }
}

// ---- fp16 MFMA GEMM: A fp16, B fp32 converted inline (proj) ----
template <int BMT, int BNT>
__global__ __launch_bounds__(256) void gemm_a16b32(
    const _Float16* __restrict__ A, const float* __restrict__ B,
    const float* __restrict__ bias, float* __restrict__ C,
    int M, int N, int K)
{
    constexpr int IT = BMT / 32;
    constexpr int JT = BNT / 32;
    constexpr int AU = BMT / 64;
    constexpr int BU = BNT / 64;
    __shared__ _Float16 AhS[BMT * 32];
    __shared__ _Float16 BhS[BNT * 32];

    const int tid = threadIdx.x;
    const int w = tid >> 6;
    const int lane = tid & 63;
    const int l15 = lane & 15;
    const int quad = lane >> 4;
    const int wm = w >> 1, wn = w & 1;
    const int bm = blockIdx.y * BMT;
    const int bn = blockIdx.x * BNT;

    f32x4 acc[IT][JT];
    #pragma unroll
    for (int i = 0; i < IT; ++i)
        #pragma unroll
        for (int j = 0; j < JT; ++j)
            acc[i][j] = (f32x4){0.f, 0.f, 0.f, 0.f};

    h16x8 rah[AU];
    float4 rbh[BU][2];
    auto loadg = [&](int k0) {
        #pragma unroll
        for (int u = 0; u < AU; ++u) {
            int c = tid + u * 256, m = c >> 2, kg = c & 3;
            rah[u] = *(const h16x8*)(A + (size_t)(bm + m) * K + k0 + kg * 8);
        }
        #pragma unroll
        for (int u = 0; u < BU; ++u) {
            int c = tid + u * 256, m = c >> 2, kg = c & 3;
            size_t off = (size_t)(bn + m) * K + k0 + kg * 8;
            rbh[u][0] = *(const float4*)(B + off);
            rbh[u][1] = *(const float4*)(B + off + 4);
        }
    };

    loadg(0);
    for (int k0 = 0; k0 < K; k0 += 32) {
        __syncthreads();
        #pragma unroll
        for (int u = 0; u < AU; ++u) {
            int c = tid + u * 256, m = c >> 2, kg = c & 3;
            *(h16x8*)&AhS[LDSA(m, kg)] = rah[u];
        }
        #pragma unroll
        for (int u = 0; u < BU; ++u) {
            int c = tid + u * 256, m = c >> 2, kg = c & 3;
            *(h16x8*)&BhS[LDSA(m, kg)] = cvt8(rbh[u][0], rbh[u][1]);
        }
        __syncthreads();
        if (k0 + 32 < K) loadg(k0 + 32);

        h16x8 af[IT], bf[JT];
        #pragma unroll
        for (int i = 0; i < IT; ++i) {
            int m = wm * (BMT / 2) + i * 16 + l15;
            af[i] = *(h16x8*)&AhS[LDSA(m, quad)];
        }
        #pragma unroll
        for (int j = 0; j < JT; ++j) {
            int n = wn * (BNT / 2) + j * 16 + l15;
            bf[j] = *(h16x8*)&BhS[LDSA(n, quad)];
        }
        #pragma unroll
        for (int i = 0; i < IT; ++i)
            #pragma unroll
            for (int j = 0; j < JT; ++j)
                acc[i][j] = __builtin_amdgcn_mfma_f32_16x16x32_f16(af[i], bf[j], acc[i][j], 0, 0, 0);
    }

    #pragma unroll
    for (int j = 0; j < JT; ++j) {
        int col = bn + wn * (BNT / 2) + j * 16 + l15;
        float bb = bias[col];
        #pragma unroll
        for (int i = 0; i < IT; ++i)
            #pragma unroll
            for (int r = 0; r < 4; ++r) {
                int row = bm + wm * (BMT / 2) + i * 16 + quad * 4 + r;
                C[(size_t)row * N + col] = acc[i][j][r] + bb;
            }
    }
}

// ---------------- RoPE + scatter -> bf16 q (pre-scaled), k, v ----------------
__global__ __launch_bounds__(256) void rope_scatter_bf16(
    const float* __restrict__ qkv, const float* __restrict__ rpe,
    short* __restrict__ q, short* __restrict__ k, short* __restrict__ v)
{
    __shared__ float cs[40], sn[40];
    const int s = blockIdx.x;
    if (threadIdx.x < 40)
        __sincosf(rpe[s * 40 + threadIdx.x], &sn[threadIdx.x], &cs[threadIdx.x]);
    __syncthreads();
    const float scale = 0.11180339887498949f;  // 80^-0.5
    for (int j = threadIdx.x; j < ND3; j += 256) {
        int p = j / DD;
        int rem = j - p * DD;
        int hh = rem / HDD;
        int d = rem - hh * HDD;
        float x = qkv[(size_t)s * ND3 + j];
        float val;
        if (p == 2) {
            val = x;
        } else {
            int dm = (d < 40) ? d : d - 40;
            float other = (d < 40)
                ? -qkv[(size_t)s * ND3 + p * DD + hh * HDD + d + 40]
                :  qkv[(size_t)s * ND3 + p * DD + hh * HDD + d - 40];
            val = x * cs[dm] + other * sn[dm];
            if (p == 0) val *= scale;
        }
        short* dst = (p == 0) ? q : (p == 1) ? k : v;
        dst[((size_t)hh * SS + s) * HDD + d] = f2bf(val);
    }
}

// ---- flash attention: R8 16-row shape + R9 swizzled Vts, z=2, fp32 partials --
// LDS = Ks 13312 + Vts 10240 + Ps 9216 = 32768 B -> 5 blocks/CU.
__global__ __launch_bounds__(256) void attn_mfma(
    const short* __restrict__ q, const short* __restrict__ k,
    const short* __restrict__ v, float* __restrict__ o_part,
    float* __restrict__ l_part)
{
    __shared__ short Ks[64][104];    // keys x dims, pad cols 80..95 zeroed
    __shared__ short Vts[80 * 64];   // dims x keys, XOR-swizzled octets
    __shared__ short Ps[4][16][72];  // per-wave P tile

    const int h = blockIdx.y;
    const int q0 = blockIdx.x << 6;
    const int z = blockIdx.z;
    const int tid = threadIdx.x;
    const int w = tid >> 6;
    const int lane = tid & 63;
    const int l15 = lane & 15;
    const int quad = lane >> 4;

    const short* qbase = q + (size_t)h * SS * HDD;
    const short* kbase = k + (size_t)h * SS * HDD;
    const short* vbase = v + (size_t)h * SS * HDD;

    short8 qf[3];
    {
        const int row = q0 + w * 16 + l15;
        #pragma unroll
        for (int kk = 0; kk < 3; ++kk) {
            int c0 = kk * 32 + quad * 8;
            qf[kk] = (c0 < HDD) ? *(const short8*)(qbase + (size_t)row * HDD + c0)
                                : (short8)0;
        }
    }

    if (tid < 128) {   // zero K pad cols 80..95
        int r = tid >> 1, c = 80 + (tid & 1) * 8;
        *(short8*)&Ks[r][c] = (short8)0;
    }

    float lsum[4] = {0.f, 0.f, 0.f, 0.f};
    f32x4 o[5];
    #pragma unroll
    for (int n = 0; n < 5; ++n) o[n] = (f32x4){0.f, 0.f, 0.f, 0.f};

    const int kt0 = z << 10;
    for (int kt = kt0; kt < kt0 + 1024; kt += 64) {
        __syncthreads();
        // ---- stage K tile ----
        #pragma unroll
        for (int u = 0; u < 3; ++u) {
            int i = tid + u * 256;
            if (i < 640) {
                int r = i / 10, c = (i - r * 10) * 8;
                *(short8*)&Ks[r][c] = *(const short8*)(kbase + (size_t)(kt + r) * HDD + c);
            }
        }
        // ---- stage V transposed into swizzled Vts ----
        #pragma unroll
        for (int u = 0; u < 2; ++u) {
            int task = tid + u * 256;
            if (task < 320) {
                int r4 = (task & 15) << 2;
                int d4 = (task >> 4) << 2;
                s16x4 a0 = *(const s16x4*)(vbase + (size_t)(kt + r4 + 0) * HDD + d4);
                s16x4 a1 = *(const s16x4*)(vbase + (size_t)(kt + r4 + 1) * HDD + d4);
                s16x4 a2 = *(const s16x4*)(vbase + (size_t)(kt + r4 + 2) * HDD + d4);
                s16x4 a3 = *(const s16x4*)(vbase + (size_t)(kt + r4 + 3) * HDD + d4);
                #pragma unroll
                for (int j = 0; j < 4; ++j) {
                    s16x4 w4 = {a0[j], a1[j], a2[j], a3[j]};
                    int d = d4 + j;
                    int sw = (r4 >> 3) ^ (d & 7);
                    *(s16x4*)&Vts[d * 64 + sw * 8 + (r4 & 7)] = w4;
                }
            }
        }
        __syncthreads();

        // ---- QK^T ----
        f32x4 s_[4];
        #pragma unroll
        for (int nt = 0; nt < 4; ++nt) {
            f32x4 acc = (f32x4){0.f, 0.f, 0.f, 0.f};
            #pragma unroll
            for (int kk = 0; kk < 3; ++kk) {
                short8 bf = *(short8*)&Ks[nt * 16 + l15][kk * 32 + quad * 8];
                acc = __builtin_amdgcn_mfma_f32_16x16x32_bf16(qf[kk], bf, acc, 0, 0, 0);
            }
            s_[nt] = acc;
        }

        // ---- p = exp(s - 16), partial sums, P -> LDS ----
        #pragma unroll
        for (int nt = 0; nt < 4; ++nt)
            #pragma unroll
            for (int r = 0; r < 4; ++r) {
                float p = __expf(s_[nt][r] - 16.f);
                lsum[r] += p;
                Ps[w][quad * 4 + r][nt * 16 + l15] = f2bf(p);
            }

        // ---- P -> A-operand, PV with swizzled V reads ----
        short8 pf[2];
        #pragma unroll
        for (int kk = 0; kk < 2; ++kk)
            pf[kk] = *(short8*)&Ps[w][l15][kk * 32 + quad * 8];
        #pragma unroll
        for (int n = 0; n < 5; ++n) {
            #pragma unroll
            for (int kk = 0; kk < 2; ++kk) {
                int d = n * 16 + l15;
                int sw = (kk * 4 + quad) ^ (l15 & 7);
                short8 vf = *(short8*)&Vts[d * 64 + sw * 8];
                o[n] = __builtin_amdgcn_mfma_f32_16x16x32_bf16(pf[kk], vf, o[n], 0, 0, 0);
            }
        }
    }

    // ---- deferred l-reduction + fp32 partial stores ----
    #pragma unroll
    for (int r = 0; r < 4; ++r) {
        float rs = lsum[r];
        #pragma unroll
        for (int off = 1; off < 16; off <<= 1)
            rs += __shfl_xor(rs, off, 64);
        lsum[r] = rs;
    }

    float* ob = o_part + (size_t)z * SS * DD;
    #pragma unroll
    for (int n = 0; n < 5; ++n)
        #pragma unroll
        for (int r = 0; r < 4; ++r) {
            int row = q0 + w * 16 + quad * 4 + r;
            ob[(size_t)row * DD + h * HDD + n * 16 + l15] = o[n][r];
        }
    if (l15 == 0)
        #pragma unroll
        for (int r = 0; r < 4; ++r)
            l_part[((size_t)z * HH + h) * SS + q0 + w * 16 + quad * 4 + r] = lsum[r];
}

// ---------------- merge K-split halves, emit fp16 ----------------
__global__ __launch_bounds__(256) void attn_merge(
    const float* __restrict__ o_part, const float* __restrict__ l_part,
    _Float16* __restrict__ oh)
{
    int i = (blockIdx.x * 256 + threadIdx.x) * 4;
    int row = i / DD;
    int col = i - row * DD;
    int h = col / HDD;
    float4 a = *(const float4*)(o_part + i);
    float4 b = *(const float4*)(o_part + (size_t)SS * DD + i);
    float l = l_part[h * SS + row] + l_part[(HH + h) * SS + row];
    float inv = 1.f / l;
    h16x4 hv;
    hv[0] = (_Float16)((a.x + b.x) * inv);
    hv[1] = (_Float16)((a.y + b.y) * inv);
    hv[2] = (_Float16)((a.z + b.z) * inv);
    hv[3] = (_Float16)((a.w + b.w) * inv);
    *(h16x4*)(oh + i) = hv;
}

extern "C" void kernel_launch(void* const* d_in, const int* in_sizes, int n_in,
                              void* d_out, int out_size, void* d_ws, size_t ws_size,
                              hipStream_t stream)
{
    const float* hs     = (const float*)d_in[0];
    const float* rpe    = (const float*)d_in[1];
    const float* qkv_w  = (const float*)d_in[2];
    const float* qkv_b  = (const float*)d_in[3];
    const float* proj_w = (const float*)d_in[4];
    const float* proj_b = (const float*)d_in[5];
    float* out = (float*)d_out;

    // ---- workspace layout (47.2 MB, region-aliased; 2-byte units) ----
    short* s0 = (short*)d_ws;                   // R0: 15,728,640 units
    float* qkv_f  = (float*)d_ws;               //   [S][3D] fp32, dead after rope
    float* o_part = (float*)d_ws;               //   R0 reuse: 2 x S x D fp32 partials
    float* l_part = (float*)d_ws + 5242880;     //   2 x H x S fp32
    short* s1 = s0 + 15728640;                  // R1: 7,864,320 units
    short* qb = s1;
    short* kb = s1 + 2621440;
    short* vb = s1 + 5242880;
    _Float16* attn_h = (_Float16*)s1;           //   R1 reuse after attn (aliases qb)

    // QKV GEMM: fp32 inputs, inline fp16 convert; 128x128, grid (30,16)
    gemm_f32ab<128, 128><<<dim3(ND3 / 128, SS / 128), 256, 0, stream>>>(
        hs, qkv_w, qkv_b, qkv_f, SS, ND3, DD);
    rope_scatter_bf16<<<SS, 256, 0, stream>>>(qkv_f, rpe, qb, kb, vb);
    attn_mfma<<<dim3(SS / 64, HH, 2), 256, 0, stream>>>(qb, kb, vb, o_part, l_part);
    attn_merge<<<(SS * DD) / 1024, 256, 0, stream>>>(o_part, l_part, attn_h);
    // proj GEMM: A fp16, B fp32 inline; 64x128, grid (10,32)
    gemm_a16b32<64, 128><<<dim3(DD / 128, SS / 64), 256, 0, stream>>>(
        attn_h, proj_w, proj_b, out, SS, DD, DD);
}

// Round 12
// 211.850 us; speedup vs baseline: 1.0823x; 1.0823x over previous
//
#include <hip/hip_runtime.h>
#include <math.h>

#define SS 2048
#define DD 1280
#define HH 16
#define HDD 80
#define ND3 3840

typedef __attribute__((ext_vector_type(8))) short short8;
typedef __attribute__((ext_vector_type(4))) short s16x4;
typedef __attribute__((ext_vector_type(4))) float f32x4;
typedef __attribute__((ext_vector_type(8))) _Float16 h16x8;
typedef __attribute__((ext_vector_type(4))) _Float16 h16x4;

__device__ inline short f2bf(float f) {
    union { float f; unsigned u; } x; x.f = f;
    unsigned r = x.u + 0x7FFF + ((x.u >> 16) & 1);
    return (short)(r >> 16);
}

// ---------------- fused convert: three fp32 arrays -> fp16 ----------------
__global__ __launch_bounds__(256) void split_f16(
    const float* __restrict__ a, _Float16* __restrict__ ah, int nbA,
    const float* __restrict__ b, _Float16* __restrict__ bh, int nbB,
    const float* __restrict__ c, _Float16* __restrict__ ch)
{
    const float* x; _Float16* h;
    int blk = blockIdx.x;
    if (blk < nbA)            { x = a; h = ah; }
    else if (blk < nbA + nbB) { blk -= nbA; x = b; h = bh; }
    else                      { blk -= nbA + nbB; x = c; h = ch; }
    int i = (blk * 256 + threadIdx.x) * 4;
    float4 v = *(const float4*)(x + i);
    h16x4 hv;
    hv[0] = (_Float16)v.x; hv[1] = (_Float16)v.y;
    hv[2] = (_Float16)v.z; hv[3] = (_Float16)v.w;
    *(h16x4*)(h + i) = hv;
}

#define LDSA(m, kg) ((m) * 32 + (((kg) ^ (((m) >> 1) & 3)) << 3))

// ---------------- fp16 MFMA GEMM (R8-proven): C = A @ B^T + bias ----------------
template <int BMT, int BNT>
__global__ __launch_bounds__(256) void gemm_f16(
    const _Float16* __restrict__ Ah, const _Float16* __restrict__ Bh,
    const float* __restrict__ bias, float* __restrict__ C,
    int M, int N, int K)
{
    constexpr int IT = BMT / 32;
    constexpr int JT = BNT / 32;
    constexpr int AU = BMT / 64;
    constexpr int BU = BNT / 64;
    __shared__ _Float16 AhS[BMT * 32];
    __shared__ _Float16 BhS[BNT * 32];

    const int tid = threadIdx.x;
    const int w = tid >> 6;
    const int lane = tid & 63;
    const int l15 = lane & 15;
    const int quad = lane >> 4;
    const int wm = w >> 1, wn = w & 1;
    const int bm = blockIdx.y * BMT;
    const int bn = blockIdx.x * BNT;

    f32x4 acc[IT][JT];
    #pragma unroll
    for (int i = 0; i < IT; ++i)
        #pragma unroll
        for (int j = 0; j < JT; ++j)
            acc[i][j] = (f32x4){0.f, 0.f, 0.f, 0.f};

    h16x8 rah[AU], rbh[BU];
    auto loadg = [&](int k0) {
        #pragma unroll
        for (int u = 0; u < AU; ++u) {
            int c = tid + u * 256, m = c >> 2, kg = c & 3;
            rah[u] = *(const h16x8*)(Ah + (size_t)(bm + m) * K + k0 + kg * 8);
        }
        #pragma unroll
        for (int u = 0; u < BU; ++u) {
            int c = tid + u * 256, m = c >> 2, kg = c & 3;
            rbh[u] = *(const h16x8*)(Bh + (size_t)(bn + m) * K + k0 + kg * 8);
        }
    };

    loadg(0);
    for (int k0 = 0; k0 < K; k0 += 32) {
        __syncthreads();
        #pragma unroll
        for (int u = 0; u < AU; ++u) {
            int c = tid + u * 256, m = c >> 2, kg = c & 3;
            *(h16x8*)&AhS[LDSA(m, kg)] = rah[u];
        }
        #pragma unroll
        for (int u = 0; u < BU; ++u) {
            int c = tid + u * 256, m = c >> 2, kg = c & 3;
            *(h16x8*)&BhS[LDSA(m, kg)] = rbh[u];
        }
        __syncthreads();
        if (k0 + 32 < K) loadg(k0 + 32);

        h16x8 af[IT], bf[JT];
        #pragma unroll
        for (int i = 0; i < IT; ++i) {
            int m = wm * (BMT / 2) + i * 16 + l15;
            af[i] = *(h16x8*)&AhS[LDSA(m, quad)];
        }
        #pragma unroll
        for (int j = 0; j < JT; ++j) {
            int n = wn * (BNT / 2) + j * 16 + l15;
            bf[j] = *(h16x8*)&BhS[LDSA(n, quad)];
        }
        #pragma unroll
        for (int i = 0; i < IT; ++i)
            #pragma unroll
            for (int j = 0; j < JT; ++j)
                acc[i][j] = __builtin_amdgcn_mfma_f32_16x16x32_f16(af[i], bf[j], acc[i][j], 0, 0, 0);
    }

    #pragma unroll
    for (int j = 0; j < JT; ++j) {
        int col = bn + wn * (BNT / 2) + j * 16 + l15;
        float bb = bias[col];
        #pragma unroll
        for (int i = 0; i < IT; ++i)
            #pragma unroll
            for (int r = 0; r < 4; ++r) {
                int row = bm + wm * (BMT / 2) + i * 16 + quad * 4 + r;
                C[(size_t)row * N + col] = acc[i][j][r] + bb;
            }
    }
}

// ---- proj GEMM with fused attention-merge in A-staging ----
// A[m][k] = (o0[m][k] + o1[m][k]) * inv_l[head(k)][m], converted fp16 in LDS.
// inv_l built once per block into LDS (16 heads x 64 rows).
__global__ __launch_bounds__(256) void gemm_proj_merge(
    const _Float16* __restrict__ o_part, const float* __restrict__ l_part,
    const _Float16* __restrict__ Bh,
    const float* __restrict__ bias, float* __restrict__ C,
    int M, int N, int K)
{
    constexpr int BMT = 64, BNT = 128;
    constexpr int JT = BNT / 32;
    constexpr int BU = BNT / 64;
    __shared__ _Float16 AhS[BMT * 32];
    __shared__ _Float16 BhS[BNT * 32];
    __shared__ float linvS[HH * 64];

    const int tid = threadIdx.x;
    const int w = tid >> 6;
    const int lane = tid & 63;
    const int l15 = lane & 15;
    const int quad = lane >> 4;
    const int wm = w >> 1, wn = w & 1;
    const int bm = blockIdx.y * BMT;
    const int bn = blockIdx.x * BNT;

    // build inv-l table: 16 heads x 64 rows
    for (int i = tid; i < HH * 64; i += 256) {
        int h = i >> 6, r = i & 63;
        float l0 = l_part[(size_t)h * SS + bm + r];
        float l1 = l_part[(size_t)(HH + h) * SS + bm + r];
        linvS[i] = 1.f / (l0 + l1);
    }

    f32x4 acc[2][JT];
    #pragma unroll
    for (int i = 0; i < 2; ++i)
        #pragma unroll
        for (int j = 0; j < JT; ++j)
            acc[i][j] = (f32x4){0.f, 0.f, 0.f, 0.f};

    h16x8 ra0, ra1, rbh[BU];
    auto loadg = [&](int k0) {
        {
            int m = tid >> 2, kg = tid & 3;
            size_t off = (size_t)(bm + m) * K + k0 + kg * 8;
            ra0 = *(const h16x8*)(o_part + off);
            ra1 = *(const h16x8*)(o_part + (size_t)SS * DD + off);
        }
        #pragma unroll
        for (int u = 0; u < BU; ++u) {
            int c = tid + u * 256, m = c >> 2, kg = c & 3;
            rbh[u] = *(const h16x8*)(Bh + (size_t)(bn + m) * K + k0 + kg * 8);
        }
    };

    loadg(0);
    for (int k0 = 0; k0 < K; k0 += 32) {
        __syncthreads();
        {
            int m = tid >> 2, kg = tid & 3;
            int koff = k0 + kg * 8;
            int h = koff / HDD;                 // 8-elem chunk stays in one head
            float inv = linvS[h * 64 + m];
            h16x8 f;
            #pragma unroll
            for (int e = 0; e < 8; ++e)
                f[e] = (_Float16)(((float)ra0[e] + (float)ra1[e]) * inv);
            *(h16x8*)&AhS[LDSA(m, kg)] = f;
        }
        #pragma unroll
        for (int u = 0; u < BU; ++u) {
            int c = tid + u * 256, m = c >> 2, kg = c & 3;
            *(h16x8*)&BhS[LDSA(m, kg)] = rbh[u];
        }
        __syncthreads();
        if (k0 + 32 < K) loadg(k0 + 32);

        h16x8 af[2], bf[JT];
        #pragma unroll
        for (int i = 0; i < 2; ++i) {
            int m = wm * 32 + i * 16 + l15;
            af[i] = *(h16x8*)&AhS[LDSA(m, quad)];
        }
        #pragma unroll
        for (int j = 0; j < JT; ++j) {
            int n = wn * 64 + j * 16 + l15;
            bf[j] = *(h16x8*)&BhS[LDSA(n, quad)];
        }
        #pragma unroll
        for (int i = 0; i < 2; ++i)
            #pragma unroll
            for (int j = 0; j < JT; ++j)
                acc[i][j] = __builtin_amdgcn_mfma_f32_16x16x32_f16(af[i], bf[j], acc[i][j], 0, 0, 0);
    }

    #pragma unroll
    for (int j = 0; j < JT; ++j) {
        int col = bn + wn * 64 + j * 16 + l15;
        float bb = bias[col];
        #pragma unroll
        for (int i = 0; i < 2; ++i)
            #pragma unroll
            for (int r = 0; r < 4; ++r) {
                int row = bm + wm * 32 + i * 16 + quad * 4 + r;
                C[(size_t)row * N + col] = acc[i][j][r] + bb;
            }
    }
}

// ---------------- RoPE + scatter, 4-wide vectorized ----------------
__global__ __launch_bounds__(256) void rope_scatter_bf16(
    const float* __restrict__ qkv, const float* __restrict__ rpe,
    short* __restrict__ q, short* __restrict__ k, short* __restrict__ v)
{
    __shared__ __align__(16) float cs[40], sn[40];
    const int s = blockIdx.x;
    if (threadIdx.x < 40)
        __sincosf(rpe[s * 40 + threadIdx.x], &sn[threadIdx.x], &cs[threadIdx.x]);
    __syncthreads();
    const float scale = 0.11180339887498949f;  // 80^-0.5
    const float* src = qkv + (size_t)s * ND3;
    for (int t = threadIdx.x; t < ND3 / 4; t += 256) {
        int j4 = t * 4;
        int p = j4 / DD;
        int rem = j4 - p * DD;
        int hh = rem / HDD;
        int d = rem - hh * HDD;
        float4 x = *(const float4*)(src + j4);
        float vv[4];
        if (p == 2) {
            vv[0] = x.x; vv[1] = x.y; vv[2] = x.z; vv[3] = x.w;
        } else {
            bool lo = d < 40;
            int dm = lo ? d : d - 40;
            float4 oth = *(const float4*)(src + p * DD + hh * HDD + (lo ? d + 40 : d - 40));
            float4 c4 = *(const float4*)&cs[dm];
            float4 s4 = *(const float4*)&sn[dm];
            float sg = lo ? -1.f : 1.f;
            vv[0] = x.x * c4.x + sg * oth.x * s4.x;
            vv[1] = x.y * c4.y + sg * oth.y * s4.y;
            vv[2] = x.z * c4.z + sg * oth.z * s4.z;
            vv[3] = x.w * c4.w + sg * oth.w * s4.w;
            if (p == 0) { vv[0] *= scale; vv[1] *= scale; vv[2] *= scale; vv[3] *= scale; }
        }
        short* dst = (p == 0) ? q : (p == 1) ? k : v;
        s16x4 o4;
        o4[0] = f2bf(vv[0]); o4[1] = f2bf(vv[1]);
        o4[2] = f2bf(vv[2]); o4[3] = f2bf(vv[3]);
        *(s16x4*)(dst + ((size_t)hh * SS + s) * HDD + d) = o4;
    }
}

// ---- flash attention (R9 champion): 32 rows/wave, z=2, swizzled Vts ----
// Delta vs R9: fixed max 8, fp16 partial o stores.
__global__ __launch_bounds__(256) void attn_mfma(
    const short* __restrict__ q, const short* __restrict__ k,
    const short* __restrict__ v, _Float16* __restrict__ o_part,
    float* __restrict__ l_part)
{
    __shared__ short Ks[64][104];     // keys x dims (pad cols 80..95 zeroed)
    __shared__ short Vts[80 * 64];    // dims x keys, XOR-swizzled octets
    __shared__ short Ps[4][32][72];   // per-wave P tile

    const int h = blockIdx.y;
    const int q0 = blockIdx.x << 7;   // 128 rows per block
    const int z = blockIdx.z;
    const int tid = threadIdx.x;
    const int w = tid >> 6;
    const int lane = tid & 63;
    const int l15 = lane & 15;
    const int quad = lane >> 4;

    const short* qbase = q + (size_t)h * SS * HDD;
    const short* kbase = k + (size_t)h * SS * HDD;
    const short* vbase = v + (size_t)h * SS * HDD;

    short8 qf[2][3];
    #pragma unroll
    for (int i = 0; i < 2; ++i) {
        const int row = q0 + w * 32 + i * 16 + l15;
        #pragma unroll
        for (int kk = 0; kk < 3; ++kk) {
            int c0 = kk * 32 + quad * 8;
            qf[i][kk] = (c0 < HDD) ? *(const short8*)(qbase + (size_t)row * HDD + c0)
                                   : (short8)0;
        }
    }

    if (tid < 128) {   // zero K pad cols 80..95
        int r = tid >> 1, c = 80 + (tid & 1) * 8;
        *(short8*)&Ks[r][c] = (short8)0;
    }

    float lsum[2][4] = {{0.f}};
    f32x4 o[2][5];
    #pragma unroll
    for (int i = 0; i < 2; ++i)
        #pragma unroll
        for (int n = 0; n < 5; ++n) o[i][n] = (f32x4){0.f, 0.f, 0.f, 0.f};

    const int kt0 = z << 10;
    for (int kt = kt0; kt < kt0 + 1024; kt += 64) {
        __syncthreads();
        #pragma unroll
        for (int u = 0; u < 3; ++u) {
            int i = tid + u * 256;
            if (i < 640) {
                int r = i / 10, c = (i - r * 10) * 8;
                *(short8*)&Ks[r][c] = *(const short8*)(kbase + (size_t)(kt + r) * HDD + c);
            }
        }
        #pragma unroll
        for (int u = 0; u < 2; ++u) {
            int task = tid + u * 256;
            if (task < 320) {
                int r4 = (task & 15) << 2;
                int d4 = (task >> 4) << 2;
                s16x4 a0 = *(const s16x4*)(vbase + (size_t)(kt + r4 + 0) * HDD + d4);
                s16x4 a1 = *(const s16x4*)(vbase + (size_t)(kt + r4 + 1) * HDD + d4);
                s16x4 a2 = *(const s16x4*)(vbase + (size_t)(kt + r4 + 2) * HDD + d4);
                s16x4 a3 = *(const s16x4*)(vbase + (size_t)(kt + r4 + 3) * HDD + d4);
                #pragma unroll
                for (int j = 0; j < 4; ++j) {
                    s16x4 w4 = {a0[j], a1[j], a2[j], a3[j]};
                    int d = d4 + j;
                    int sw = (r4 >> 3) ^ (d & 7);
                    *(s16x4*)&Vts[d * 64 + sw * 8 + (r4 & 7)] = w4;
                }
            }
        }
        __syncthreads();

        f32x4 s_[2][4];
        #pragma unroll
        for (int nt = 0; nt < 4; ++nt) {
            short8 bf0 = *(short8*)&Ks[nt * 16 + l15][quad * 8];
            short8 bf1 = *(short8*)&Ks[nt * 16 + l15][32 + quad * 8];
            short8 bf2 = *(short8*)&Ks[nt * 16 + l15][64 + quad * 8];
            #pragma unroll
            for (int i = 0; i < 2; ++i) {
                f32x4 acc = (f32x4){0.f, 0.f, 0.f, 0.f};
                acc = __builtin_amdgcn_mfma_f32_16x16x32_bf16(qf[i][0], bf0, acc, 0, 0, 0);
                acc = __builtin_amdgcn_mfma_f32_16x16x32_bf16(qf[i][1], bf1, acc, 0, 0, 0);
                acc = __builtin_amdgcn_mfma_f32_16x16x32_bf16(qf[i][2], bf2, acc, 0, 0, 0);
                s_[i][nt] = acc;
            }
        }

        #pragma unroll
        for (int i = 0; i < 2; ++i)
            #pragma unroll
            for (int nt = 0; nt < 4; ++nt)
                #pragma unroll
                for (int r = 0; r < 4; ++r) {
                    float p = __expf(s_[i][nt][r] - 8.f);
                    lsum[i][r] += p;
                    Ps[w][i * 16 + quad * 4 + r][nt * 16 + l15] = f2bf(p);
                }

        short8 pf[2][2];
        #pragma unroll
        for (int i = 0; i < 2; ++i)
            #pragma unroll
            for (int kk = 0; kk < 2; ++kk)
                pf[i][kk] = *(short8*)&Ps[w][i * 16 + l15][kk * 32 + quad * 8];
        #pragma unroll
        for (int n = 0; n < 5; ++n) {
            #pragma unroll
            for (int kk = 0; kk < 2; ++kk) {
                int d = n * 16 + l15;
                int sw = (kk * 4 + quad) ^ (l15 & 7);
                short8 vf = *(short8*)&Vts[d * 64 + sw * 8];
                #pragma unroll
                for (int i = 0; i < 2; ++i)
                    o[i][n] = __builtin_amdgcn_mfma_f32_16x16x32_bf16(pf[i][kk], vf, o[i][n], 0, 0, 0);
            }
        }
    }

    _Float16* ob = o_part + (size_t)z * SS * DD;
    #pragma unroll
    for (int i = 0; i < 2; ++i) {
        #pragma unroll
        for (int r = 0; r < 4; ++r) {
            float rs = lsum[i][r];
            #pragma unroll
            for (int off = 1; off < 16; off <<= 1)
                rs += __shfl_xor(rs, off, 64);
            lsum[i][r] = rs;
        }
        #pragma unroll
        for (int n = 0; n < 5; ++n)
            #pragma unroll
            for (int r = 0; r < 4; ++r) {
                int row = q0 + w * 32 + i * 16 + quad * 4 + r;
                ob[(size_t)row * DD + h * HDD + n * 16 + l15] = (_Float16)o[i][n][r];
            }
        if (l15 == 0)
            #pragma unroll
            for (int r = 0; r < 4; ++r)
                l_part[((size_t)z * HH + h) * SS + q0 + w * 32 + i * 16 + quad * 4 + r] = lsum[i][r];
    }
}

extern "C" void kernel_launch(void* const* d_in, const int* in_sizes, int n_in,
                              void* d_out, int out_size, void* d_ws, size_t ws_size,
                              hipStream_t stream)
{
    const float* hs     = (const float*)d_in[0];
    const float* rpe    = (const float*)d_in[1];
    const float* qkv_w  = (const float*)d_in[2];
    const float* qkv_b  = (const float*)d_in[3];
    const float* proj_w = (const float*)d_in[4];
    const float* proj_b = (const float*)d_in[5];
    float* out = (float*)d_out;

    // ---- workspace layout (55.7 MB, region-aliased; 2-byte units) ----
    short* s0 = (short*)d_ws;                   // R0: 15,728,640 units
    float* qkv_f  = (float*)d_ws;               //   [S][3D] fp32, dead after rope
    _Float16* o_part = (_Float16*)s0;           //   R0 reuse: 2 x S x D fp16 partials
    float* l_part = (float*)(s0 + 10485760);    //   2 x H x S fp32
    short* s1 = s0 + 15728640;                  // R1: 7,864,320 units
    _Float16* qkvw_h = (_Float16*)s1;           //   dead after gemm1
    short* qb = s1;                             //   R1 reuse after gemm1
    short* kb = s1 + 2621440;
    short* vb = s1 + 5242880;
    short* s2 = s1 + 7864320;                   // R2: 2,621,440 units
    _Float16* hs_h = (_Float16*)s2;
    short* s3 = s2 + 2621440;                   // R3: 1,638,400 units
    _Float16* projw_h = (_Float16*)s3;

    const int n_hs = SS * DD;        // 2,621,440 -> 2560 blocks
    const int n_qw = ND3 * DD;       // 4,915,200 -> 4800 blocks
    const int n_pw = DD * DD;        // 1,638,400 -> 1600 blocks

    split_f16<<<n_hs / 1024 + n_qw / 1024 + n_pw / 1024, 256, 0, stream>>>(
        hs, hs_h, n_hs / 1024,
        qkv_w, qkvw_h, n_qw / 1024,
        proj_w, projw_h);
    gemm_f16<128, 128><<<dim3(ND3 / 128, SS / 128), 256, 0, stream>>>(
        hs_h, qkvw_h, qkv_b, qkv_f, SS, ND3, DD);
    rope_scatter_bf16<<<SS, 256, 0, stream>>>(qkv_f, rpe, qb, kb, vb);
    attn_mfma<<<dim3(SS / 128, HH, 2), 256, 0, stream>>>(qb, kb, vb, o_part, l_part);
    gemm_proj_merge<<<dim3(DD / 128, SS / 64), 256, 0, stream>>>(
        o_part, l_part, projw_h, proj_b, out, SS, DD, DD);
}